// Round 5
// baseline (176.368 us; speedup 1.0000x reference)
//
#include <hip/hip_runtime.h>

constexpr int Bn = 2;
constexpr int Ln = 1024;
constexpr int Dn = 768;
constexpr int Hn = 128;          // MLP_HIDDEN
constexpr int KM1 = 63;          // K-1
constexpr int Wn = 961;          // windows
constexpr int RB = 4;            // rows per block (gemm1)
constexpr int WB = 4;            // windows per block (fused)
constexpr int WCHUNKS = (Wn + WB - 1) / WB;  // 241
constexpr int NROW = Bn * Wn;    // 1922
constexpr int FGRID = Bn * WCHUNKS;          // 482
constexpr float EPSf = 1e-8f;

__device__ __forceinline__ float4 f4l(const float* p) { return *reinterpret_cast<const float4*>(p); }
__device__ __forceinline__ void f4s(float* p, float4 v) { *reinterpret_cast<float4*>(p) = v; }
__device__ __forceinline__ float4 f4fma(float s, float4 w, float4 a) {
    a.x = fmaf(s, w.x, a.x); a.y = fmaf(s, w.y, a.y);
    a.z = fmaf(s, w.z, a.z); a.w = fmaf(s, w.w, a.w);
    return a;
}

// ---------------------------------------------------------------------------
// Kernel A: xw1 = x @ w1[:D] (2048 rows, 512 blocks) ;
//           pew1 = pos_emb @ w1[D:] + b1 (63 rows, 16 blocks) ; head-row copy.
// 512 thr = h4(32) x ks(16, 48-col slices); each thread all 4 rows ->
// w1 read once per block. Block 0 also zero-inits accum[0..3] + ticket.
// ---------------------------------------------------------------------------
__global__ __launch_bounds__(512)
void k_gemm1(const float* __restrict__ x, const float* __restrict__ pos_emb,
             const float* __restrict__ w1, const float* __restrict__ b1,
             float* __restrict__ xw1, float* __restrict__ pew1,
             float* __restrict__ out, float* __restrict__ accum)
{
    __shared__ float xs[RB * Dn];            // 12 KB
    __shared__ float part[16 * RB * Hn];     // 32 KB
    const int tid = threadIdx.x;
    const int h4 = tid & 31;                 // h = 4*h4
    const int ks = tid >> 5;                 // 0..15, 48 cols each
    const int blk = blockIdx.x;
    constexpr int NXB = (Bn * Ln) / RB;      // 512
    const bool isX = blk < NXB;
    const int peb = blk - NXB;

    if (blk == 0 && tid < 5) accum[tid] = 0.0f;   // accum[0..3] + ticket (bits 0)

    const float* src = isX ? (x + blk * RB * Dn) : (pos_emb + peb * RB * Dn);
    const int nv = isX ? RB : min(RB, KM1 - peb * RB);

    for (int idx = tid; idx < nv * (Dn / 4); idx += 512)
        ((float4*)xs)[idx] = ((const float4*)src)[idx];
    __syncthreads();

    // head rows (t < K-1) pass through unchanged
    if (isX) {
        const int r0 = blk * RB;
        if ((r0 & (Ln - 1)) < KM1) {
            for (int idx = tid; idx < RB * (Dn / 4); idx += 512) {
                const int i = idx / (Dn / 4);
                const int r = r0 + i;
                if ((r & (Ln - 1)) < KM1)
                    ((float4*)out)[r * (Dn / 4) + (idx - i * (Dn / 4))] = ((const float4*)xs)[idx];
            }
        }
    }

    const int woff = isX ? 0 : Dn;
    float4 acc0 = make_float4(0.f, 0.f, 0.f, 0.f);
    float4 acc1 = acc0, acc2 = acc0, acc3 = acc0;
    const int cbase = ks * 48;
    for (int cc = 0; cc < 48; cc += 4) {
        const int c = cbase + cc;
        const float* wp = w1 + (woff + c) * Hn + 4 * h4;
        const float4 wv0 = f4l(wp);
        const float4 wv1 = f4l(wp + Hn);
        const float4 wv2 = f4l(wp + 2 * Hn);
        const float4 wv3 = f4l(wp + 3 * Hn);
        const float4 x0 = ((const float4*)xs)[(0 * Dn + c) >> 2];
        const float4 x1 = ((const float4*)xs)[(1 * Dn + c) >> 2];
        const float4 x2 = ((const float4*)xs)[(2 * Dn + c) >> 2];
        const float4 x3 = ((const float4*)xs)[(3 * Dn + c) >> 2];
        acc0 = f4fma(x0.x, wv0, acc0); acc0 = f4fma(x0.y, wv1, acc0);
        acc0 = f4fma(x0.z, wv2, acc0); acc0 = f4fma(x0.w, wv3, acc0);
        acc1 = f4fma(x1.x, wv0, acc1); acc1 = f4fma(x1.y, wv1, acc1);
        acc1 = f4fma(x1.z, wv2, acc1); acc1 = f4fma(x1.w, wv3, acc1);
        acc2 = f4fma(x2.x, wv0, acc2); acc2 = f4fma(x2.y, wv1, acc2);
        acc2 = f4fma(x2.z, wv2, acc2); acc2 = f4fma(x2.w, wv3, acc2);
        acc3 = f4fma(x3.x, wv0, acc3); acc3 = f4fma(x3.y, wv1, acc3);
        acc3 = f4fma(x3.z, wv2, acc3); acc3 = f4fma(x3.w, wv3, acc3);
    }
    ((float4*)part)[((ks * RB + 0) * Hn + 4 * h4) >> 2] = acc0;
    ((float4*)part)[((ks * RB + 1) * Hn + 4 * h4) >> 2] = acc1;
    ((float4*)part)[((ks * RB + 2) * Hn + 4 * h4) >> 2] = acc2;
    ((float4*)part)[((ks * RB + 3) * Hn + 4 * h4) >> 2] = acc3;
    __syncthreads();

    // reduce 16 k-slices: thread -> (row i = tid>>7, h = tid&127)
    const int oi = tid >> 7;
    const int oh = tid & 127;
    float s = 0.f;
    #pragma unroll
    for (int k2 = 0; k2 < 16; ++k2)
        s += part[(k2 * RB + oi) * Hn + oh];
    if (isX) {
        xw1[(blk * RB + oi) * Hn + oh] = s;
    } else if (oi < nv) {
        pew1[(peb * RB + oi) * Hn + oh] = s + b1[oh];
    }
}

// ---------------------------------------------------------------------------
// Kernel B (fused): per (b, 4-window chunk) block covers the FULL 768-d row:
//   stage xw1 slab (<=66 rows) once; hbar[4][128]; 3 serial d-passes of
//   GEMM2 + update/out; register row-partials across passes; 64-lane shuffle
//   reduce per window; 3 scalar atomics; ticket -> last block writes scalars.
// 482 blocks x 256 thr, 51 KB LDS -> 3 blocks/CU.
// ---------------------------------------------------------------------------
__global__ __launch_bounds__(256)
void k_fused(const float* __restrict__ x, const float* __restrict__ alpha_p,
             const float* __restrict__ w2, const float* __restrict__ b2,
             const float* __restrict__ xw1, const float* __restrict__ pew1,
             float* __restrict__ out, float* __restrict__ accum)
{
    __shared__ float xsl[(WB + KM1 - 1) * Hn];  // 66*128 = 33 KB
    __shared__ float hsm[WB * Hn];              // 2 KB
    __shared__ float4 red[1024];                // 16 KB (shared: hbar parts / gemm2 tiles)
    __shared__ int lastFlag;

    const int tid = threadIdx.x;
    const int b = blockIdx.x / WCHUNKS;
    const int chunk = blockIdx.x % WCHUNKS;
    const int w0 = chunk * WB;
    const int wcount = min(WB, Wn - w0);
    const int nrows = wcount + KM1 - 1;         // <= 66
    const float alpha = alpha_p[0];

    // ---- stage xw1 slab once ----
    {
        const float4* src = (const float4*)(xw1 + (b * Ln + w0) * Hn);
        for (int idx = tid; idx < nrows * (Hn / 4); idx += 256)
            ((float4*)xsl)[idx] = src[idx];
    }
    __syncthreads();

    // ---- hbar: thr = kg(8) x h4(32); pew1 loaded once per k ----
    {
        const int kg = tid >> 5;
        const int h4 = tid & 31;
        float4 s[WB];
        #pragma unroll
        for (int w = 0; w < WB; ++w) s[w] = make_float4(0.f, 0.f, 0.f, 0.f);
        for (int k = kg; k < KM1; k += 8) {
            const float4 pv = f4l(pew1 + k * Hn + 4 * h4);
            #pragma unroll
            for (int w = 0; w < WB; ++w) {
                const float4 xv = ((const float4*)xsl)[((w + k) * Hn >> 2) + h4];
                s[w].x += fmaxf(xv.x + pv.x, 0.f);
                s[w].y += fmaxf(xv.y + pv.y, 0.f);
                s[w].z += fmaxf(xv.z + pv.z, 0.f);
                s[w].w += fmaxf(xv.w + pv.w, 0.f);
            }
        }
        #pragma unroll
        for (int w = 0; w < WB; ++w)
            red[(kg * WB + w) * 32 + h4] = s[w];
    }
    __syncthreads();
    if (tid < WB * 32) {
        const int w = tid >> 5;
        const int h4 = tid & 31;
        float4 t = red[w * 32 + h4];
        #pragma unroll
        for (int kg = 1; kg < 8; ++kg) {
            const float4 u = red[(kg * WB + w) * 32 + h4];
            t.x += u.x; t.y += u.y; t.z += u.z; t.w += u.w;
        }
        const float sc = 1.0f / 63.0f;
        t.x *= sc; t.y *= sc; t.z *= sc; t.w *= sc;
        ((float4*)hsm)[w * 32 + h4] = t;
    }
    __syncthreads();

    // ---- GEMM2: 3 serial d-passes; thr = hs(4) x d4(64) ----
    const int d4 = tid & 63;
    const int hs = tid >> 6;       // also wloc in combine phase (4 waves = 4 windows)
    const int wloc = hs;
    float4 pp = make_float4(0.f, 0.f, 0.f, 0.f);

    for (int dc = 0; dc < 3; ++dc) {
        float4 acc[WB];
        #pragma unroll
        for (int w = 0; w < WB; ++w) acc[w] = make_float4(0.f, 0.f, 0.f, 0.f);
        const int d = dc * 256 + d4 * 4;
        const int h0 = hs * 32;
        for (int hh = 0; hh < 32; ++hh) {
            const int h = h0 + hh;
            const float4 wv = f4l(w2 + h * Dn + d);
            #pragma unroll
            for (int w = 0; w < WB; ++w)
                acc[w] = f4fma(hsm[w * Hn + h], wv, acc[w]);
        }
        __syncthreads();   // red free (prev pass combine done / hbar reduce done)
        #pragma unroll
        for (int w = 0; w < WB; ++w)
            red[(hs * WB + w) * 64 + d4] = acc[w];
        __syncthreads();

        // combine h-splits; thread = (wloc = tid>>6, dcol = tid&63)
        if (wloc < wcount) {
            const int row = b * Ln + w0 + wloc + KM1;
            const int off = row * Dn + dc * 256 + d4 * 4;
            float4 sum = red[wloc * 64 + d4];
            #pragma unroll
            for (int k = 1; k < 4; ++k) {
                const float4 u = red[(k * WB + wloc) * 64 + d4];
                sum.x += u.x; sum.y += u.y; sum.z += u.z; sum.w += u.w;
            }
            const float4 bb = f4l(b2 + dc * 256 + d4 * 4);
            const float4 xv = f4l(x + off);
            float4 md;
            md.x = xv.x - (sum.x + bb.x);
            md.y = xv.y - (sum.y + bb.y);
            md.z = xv.z - (sum.z + bb.z);
            md.w = xv.w - (sum.w + bb.w);
            float4 nb;
            nb.x = fmaf(-alpha, md.x, xv.x);
            nb.y = fmaf(-alpha, md.y, xv.y);
            nb.z = fmaf(-alpha, md.z, xv.z);
            nb.w = fmaf(-alpha, md.w, xv.w);
            f4s(out + off, nb);
            pp.x += md.x * md.x + md.y * md.y + md.z * md.z + md.w * md.w;
            pp.y += xv.x * xv.x + xv.y * xv.y + xv.z * xv.z + xv.w * xv.w;
            pp.z += xv.x * nb.x + xv.y * nb.y + xv.z * nb.z + xv.w * nb.w;
            pp.w += nb.x * nb.x + nb.y * nb.y + nb.z * nb.z + nb.w * nb.w;
        }
    }

    // ---- per-window 64-lane reduce + scalar atomics ----
    #pragma unroll
    for (int off = 32; off > 0; off >>= 1) {
        pp.x += __shfl_xor(pp.x, off);
        pp.y += __shfl_xor(pp.y, off);
        pp.z += __shfl_xor(pp.z, off);
        pp.w += __shfl_xor(pp.w, off);
    }
    if ((tid & 63) == 0 && wloc < wcount) {
        atomicAdd(&accum[0], pp.x);                                   // sum ||md||^2
        atomicAdd(&accum[1], sqrtf(pp.x));                            // sum ||md||
        atomicAdd(&accum[2], pp.z / (fmaxf(sqrtf(pp.y), EPSf) *
                                     fmaxf(sqrtf(pp.w), EPSf)));     // sum cos
    }
    __syncthreads();

    // ---- ticket: last block finalizes the 4 scalars ----
    if (tid == 0) {
        __threadfence();
        const int old = atomicAdd((int*)(accum + 4), 1);
        lastFlag = (old == FGRID - 1) ? 1 : 0;
    }
    __syncthreads();
    if (lastFlag && tid == 0) {
        const float se = atomicAdd(&accum[0], 0.0f);
        const float sn = atomicAdd(&accum[1], 0.0f);
        const float sc = atomicAdd(&accum[2], 0.0f);
        const float inv = 1.0f / (float)NROW;
        const float pre = se * inv;
        const float om = 1.0f - alpha;
        const int base = Bn * Ln * Dn;
        out[base + 0] = pre;               // first_pre_energy
        out[base + 1] = om * om * pre;     // final_post_energy
        out[base + 2] = alpha * sn * inv;  // mean update norm
        out[base + 3] = sc * inv;          // mean cos sim
    }
}

extern "C" void kernel_launch(void* const* d_in, const int* in_sizes, int n_in,
                              void* d_out, int out_size, void* d_ws, size_t ws_size,
                              hipStream_t stream)
{
    const float* x       = (const float*)d_in[0];
    const float* alpha_p = (const float*)d_in[1];
    const float* pos_emb = (const float*)d_in[2];
    const float* w1      = (const float*)d_in[3];
    const float* b1      = (const float*)d_in[4];
    const float* w2      = (const float*)d_in[5];
    const float* b2      = (const float*)d_in[6];
    float* out = (float*)d_out;

    // ws (floats): xw1 [2048*128] | pew1 [63*128] | accum [4] + ticket [1]
    float* xw1   = (float*)d_ws;
    float* pew1  = xw1 + Bn * Ln * Hn;
    float* accum = pew1 + KM1 * Hn;

    const int nblkA = (Bn * Ln) / RB + (KM1 + RB - 1) / RB;  // 512 + 16 = 528
    k_gemm1<<<nblkA, 512, 0, stream>>>(x, pos_emb, w1, b1, xw1, pew1, out, accum);
    k_fused<<<FGRID, 256, 0, stream>>>(x, alpha_p, w2, b2, xw1, pew1, out, accum);
}

// Round 6
// 136.300 us; speedup vs baseline: 1.2940x; 1.2940x over previous
//
#include <hip/hip_runtime.h>

constexpr int Bn = 2;
constexpr int Ln = 1024;
constexpr int Dn = 768;
constexpr int Hn = 128;          // MLP_HIDDEN
constexpr int KM1 = 63;          // K-1
constexpr int Wn = 961;          // windows
constexpr int NROW = Bn * Wn;    // 1922
constexpr float EPSf = 1e-8f;

// gemm1 geometry: block = (4-row group) x (h-half of 64)
constexpr int RB1 = 4;
constexpr int NXG = (Bn * Ln) / RB1;     // 512 x row-groups
constexpr int NPEG = 16;                 // ceil(63/4) pos_emb groups
constexpr int G1 = (NXG + NPEG) * 2;     // 1088 blocks
constexpr int PSTR = 66;                 // padded part stride (floats)

// fused geometry: block = (b, 8-window chunk, 256-d chunk)
constexpr int WB = 8;
constexpr int WCH = (Wn + WB - 1) / WB;  // 121
constexpr int FG = Bn * WCH * 3;         // 726 blocks

__device__ __forceinline__ float4 f4l(const float* p) { return *reinterpret_cast<const float4*>(p); }
__device__ __forceinline__ void f4s(float* p, float4 v) { *reinterpret_cast<float4*>(p) = v; }
__device__ __forceinline__ float4 f4fma(float s, float4 w, float4 a) {
    a.x = fmaf(s, w.x, a.x); a.y = fmaf(s, w.y, a.y);
    a.z = fmaf(s, w.z, a.z); a.w = fmaf(s, w.w, a.w);
    return a;
}

// ---------------------------------------------------------------------------
// Kernel A: xw1 = x @ w1[:D]; pew1 = pos_emb @ w1[D:] + b1; head-row copy.
// 1088 blocks x 512 thr (8 waves) = 8704 waves. Thread = h4(16) x ks(32 of
// 24 cols); each thread all 4 rows -> w1 element read once per block.
// Block 0 zeroes rowacc + ticket.
// ---------------------------------------------------------------------------
__global__ __launch_bounds__(512)
void k_gemm1(const float* __restrict__ x, const float* __restrict__ pos_emb,
             const float* __restrict__ w1, const float* __restrict__ b1,
             float* __restrict__ xw1, float* __restrict__ pew1,
             float* __restrict__ out, float* __restrict__ rowacc)
{
    __shared__ float xs[RB1 * Dn];           // 12 KB
    __shared__ float part[32 * RB1 * PSTR];  // 33.8 KB
    const int tid = threadIdx.x;
    const int blk = blockIdx.x;
    const int grp = blk >> 1;                // row group
    const int hh  = blk & 1;                 // h-half (64 h each)
    const bool isX = grp < NXG;
    const int pg = grp - NXG;

    if (blk == 0) {                          // zero rowacc[NROW*4] + ticket
        for (int i = tid; i < NROW * 4 + 1; i += 512) rowacc[i] = 0.0f;
    }

    const float* src = isX ? (x + grp * RB1 * Dn) : (pos_emb + pg * RB1 * Dn);
    const int nv = isX ? RB1 : min(RB1, KM1 - pg * RB1);

    for (int idx = tid; idx < nv * (Dn / 4); idx += 512)
        ((float4*)xs)[idx] = ((const float4*)src)[idx];
    __syncthreads();

    // head rows (t < K-1) pass through unchanged (hh==0 blocks only)
    if (isX && hh == 0) {
        const int r0 = grp * RB1;
        if ((r0 & (Ln - 1)) < KM1) {
            for (int idx = tid; idx < RB1 * (Dn / 4); idx += 512) {
                const int i = idx / (Dn / 4);
                const int r = r0 + i;
                if ((r & (Ln - 1)) < KM1)
                    ((float4*)out)[r * (Dn / 4) + (idx - i * (Dn / 4))] = ((const float4*)xs)[idx];
            }
        }
    }

    const int h4 = tid & 15;                 // local h = 4*h4 (0..63)
    const int ks = tid >> 4;                 // 0..31, 24 cols each
    const int woff = isX ? 0 : Dn;
    const int hbase = hh * 64 + 4 * h4;      // global h
    float4 a0 = make_float4(0.f, 0.f, 0.f, 0.f);
    float4 a1 = a0, a2 = a0, a3 = a0;
    const int c0 = ks * 24;
    #pragma unroll
    for (int cc = 0; cc < 24; cc += 4) {
        const int c = c0 + cc;
        const float* wp = w1 + (woff + c) * Hn + hbase;
        const float4 wv0 = f4l(wp);
        const float4 wv1 = f4l(wp + Hn);
        const float4 wv2 = f4l(wp + 2 * Hn);
        const float4 wv3 = f4l(wp + 3 * Hn);
        const float4 x0 = ((const float4*)xs)[(0 * Dn + c) >> 2];
        const float4 x1 = ((const float4*)xs)[(1 * Dn + c) >> 2];
        const float4 x2 = ((const float4*)xs)[(2 * Dn + c) >> 2];
        const float4 x3 = ((const float4*)xs)[(3 * Dn + c) >> 2];
        a0 = f4fma(x0.x, wv0, a0); a0 = f4fma(x0.y, wv1, a0);
        a0 = f4fma(x0.z, wv2, a0); a0 = f4fma(x0.w, wv3, a0);
        a1 = f4fma(x1.x, wv0, a1); a1 = f4fma(x1.y, wv1, a1);
        a1 = f4fma(x1.z, wv2, a1); a1 = f4fma(x1.w, wv3, a1);
        a2 = f4fma(x2.x, wv0, a2); a2 = f4fma(x2.y, wv1, a2);
        a2 = f4fma(x2.z, wv2, a2); a2 = f4fma(x2.w, wv3, a2);
        a3 = f4fma(x3.x, wv0, a3); a3 = f4fma(x3.y, wv1, a3);
        a3 = f4fma(x3.z, wv2, a3); a3 = f4fma(x3.w, wv3, a3);
    }
    // scalar stores into padded part (2-way bank alias only)
    {
        const int hb = 4 * h4;
        float* p0 = part + (ks * RB1 + 0) * PSTR + hb;
        float* p1 = part + (ks * RB1 + 1) * PSTR + hb;
        float* p2 = part + (ks * RB1 + 2) * PSTR + hb;
        float* p3 = part + (ks * RB1 + 3) * PSTR + hb;
        p0[0] = a0.x; p0[1] = a0.y; p0[2] = a0.z; p0[3] = a0.w;
        p1[0] = a1.x; p1[1] = a1.y; p1[2] = a1.z; p1[3] = a1.w;
        p2[0] = a2.x; p2[1] = a2.y; p2[2] = a2.z; p2[3] = a2.w;
        p3[0] = a3.x; p3[1] = a3.y; p3[2] = a3.z; p3[3] = a3.w;
    }
    __syncthreads();

    if (tid < 256) {
        const int r = tid >> 6;
        const int hloc = tid & 63;
        float s = 0.f;
        #pragma unroll
        for (int k2 = 0; k2 < 32; ++k2)
            s += part[(k2 * RB1 + r) * PSTR + hloc];
        if (isX) {
            xw1[(grp * RB1 + r) * Hn + hh * 64 + hloc] = s;
        } else if (r < nv) {
            pew1[(pg * RB1 + r) * Hn + hh * 64 + hloc] = s + b1[hh * 64 + hloc];
        }
    }
}

// ---------------------------------------------------------------------------
// Kernel B (fused): per (b, 8-window chunk, 256-d chunk):
//   stage xw1 slab -> LDS; hbar (kg-split, pew1 prefetched x8);
//   GEMM2 with w2 loads batched x4; update/out; row partials -> 4 atomics;
//   ticket -> last block scans rowacc and writes the 4 scalars.
// 726 blocks x 256 thr, 71 KB LDS.
// ---------------------------------------------------------------------------
__global__ __launch_bounds__(256)
void k_fused(const float* __restrict__ x, const float* __restrict__ alpha_p,
             const float* __restrict__ w2, const float* __restrict__ b2,
             const float* __restrict__ xw1, const float* __restrict__ pew1,
             float* __restrict__ out, float* __restrict__ rowacc)
{
    __shared__ float xsl[(WB + KM1 - 1) * Hn];  // 70*128 = 35 KB
    __shared__ float hsm[WB * Hn];              // 4 KB
    __shared__ float4 red[4 * WB * 64];         // 32 KB
    __shared__ int lastFlag;

    const int tid = threadIdx.x;
    int bid = blockIdx.x;
    const int dc = bid % 3; bid /= 3;
    const int chunk = bid % WCH;
    const int b = bid / WCH;
    const int w0 = chunk * WB;
    const int wcount = min(WB, Wn - w0);
    const int nrows = wcount + KM1 - 1;         // <= 70
    const float alpha = alpha_p[0];
    int* ticket = (int*)(rowacc + NROW * 4);

    // ---- stage xw1 slab ----
    {
        const float4* src = (const float4*)(xw1 + (b * Ln + w0) * Hn);
        for (int idx = tid; idx < nrows * (Hn / 4); idx += 256)
            ((float4*)xsl)[idx] = src[idx];
    }
    __syncthreads();

    // ---- hbar: kg(8) x h4(32); pew1 prefetched (8 loads in flight) ----
    {
        const int kg = tid >> 5;
        const int h4 = tid & 31;
        float4 pv[8];
        #pragma unroll
        for (int j = 0; j < 8; ++j)              // row 63 read is in-bounds (64-row buf), unused
            pv[j] = f4l(pew1 + (kg * 8 + j) * Hn + 4 * h4);
        const int nj = (kg == 7) ? 7 : 8;
        float4 s[WB];
        #pragma unroll
        for (int w = 0; w < WB; ++w) s[w] = make_float4(0.f, 0.f, 0.f, 0.f);
        for (int j = 0; j < nj; ++j) {
            const int k = kg * 8 + j;
            #pragma unroll
            for (int w = 0; w < WB; ++w) {
                const float4 xv = ((const float4*)xsl)[(w + k) * (Hn / 4) + h4];
                s[w].x += fmaxf(xv.x + pv[j].x, 0.f);
                s[w].y += fmaxf(xv.y + pv[j].y, 0.f);
                s[w].z += fmaxf(xv.z + pv[j].z, 0.f);
                s[w].w += fmaxf(xv.w + pv[j].w, 0.f);
            }
        }
        #pragma unroll
        for (int w = 0; w < WB; ++w)
            red[(kg * WB + w) * 32 + h4] = s[w];
    }
    __syncthreads();
    {   // reduce 8 kg
        const int w = tid >> 5;
        const int h4 = tid & 31;
        float4 t = red[w * 32 + h4];
        #pragma unroll
        for (int kg = 1; kg < 8; ++kg) {
            const float4 u = red[(kg * WB + w) * 32 + h4];
            t.x += u.x; t.y += u.y; t.z += u.z; t.w += u.w;
        }
        const float sc = 1.0f / 63.0f;
        t.x *= sc; t.y *= sc; t.z *= sc; t.w *= sc;
        ((float4*)hsm)[w * 32 + h4] = t;
    }
    __syncthreads();

    // ---- GEMM2 (this dc slice): hs(4) x d4(64); w2 loads batched x4 ----
    const int d4 = tid & 63;
    const int hs = tid >> 6;
    float4 acc[WB];
    #pragma unroll
    for (int w = 0; w < WB; ++w) acc[w] = make_float4(0.f, 0.f, 0.f, 0.f);
    {
        const float* wbase = w2 + (hs * 32) * Dn + dc * 256 + d4 * 4;
        #pragma unroll
        for (int t = 0; t < 8; ++t) {
            const float4 wv0 = f4l(wbase + (4 * t + 0) * Dn);
            const float4 wv1 = f4l(wbase + (4 * t + 1) * Dn);
            const float4 wv2 = f4l(wbase + (4 * t + 2) * Dn);
            const float4 wv3 = f4l(wbase + (4 * t + 3) * Dn);
            const int h = hs * 32 + 4 * t;
            #pragma unroll
            for (int w = 0; w < WB; ++w) {
                acc[w] = f4fma(hsm[w * Hn + h + 0], wv0, acc[w]);
                acc[w] = f4fma(hsm[w * Hn + h + 1], wv1, acc[w]);
                acc[w] = f4fma(hsm[w * Hn + h + 2], wv2, acc[w]);
                acc[w] = f4fma(hsm[w * Hn + h + 3], wv3, acc[w]);
            }
        }
    }
    #pragma unroll
    for (int w = 0; w < WB; ++w)
        red[(hs * WB + w) * 64 + d4] = acc[w];
    __syncthreads();

    // ---- combine h-splits, update/out, row partials ----
    const int wloc = tid >> 5;                   // 8 windows x 32 threads
    float4 pp = make_float4(0.f, 0.f, 0.f, 0.f);
    if (wloc < wcount) {
        const int rowoff = (b * Ln + w0 + wloc + KM1) * Dn + dc * 256;
        #pragma unroll
        for (int j = 0; j < 2; ++j) {
            const int dp = (2 * tid + j) & 63;
            float4 sum = red[wloc * 64 + dp];
            #pragma unroll
            for (int k = 1; k < 4; ++k) {
                const float4 u = red[(k * WB + wloc) * 64 + dp];
                sum.x += u.x; sum.y += u.y; sum.z += u.z; sum.w += u.w;
            }
            const float4 bb = f4l(b2 + dc * 256 + dp * 4);
            const float4 xv = f4l(x + rowoff + dp * 4);
            float4 md;
            md.x = xv.x - (sum.x + bb.x);
            md.y = xv.y - (sum.y + bb.y);
            md.z = xv.z - (sum.z + bb.z);
            md.w = xv.w - (sum.w + bb.w);
            float4 nb;
            nb.x = fmaf(-alpha, md.x, xv.x);
            nb.y = fmaf(-alpha, md.y, xv.y);
            nb.z = fmaf(-alpha, md.z, xv.z);
            nb.w = fmaf(-alpha, md.w, xv.w);
            f4s(out + rowoff + dp * 4, nb);
            pp.x += md.x * md.x + md.y * md.y + md.z * md.z + md.w * md.w;
            pp.y += xv.x * xv.x + xv.y * xv.y + xv.z * xv.z + xv.w * xv.w;
            pp.z += xv.x * nb.x + xv.y * nb.y + xv.z * nb.z + xv.w * nb.w;
            pp.w += nb.x * nb.x + nb.y * nb.y + nb.z * nb.z + nb.w * nb.w;
        }
        #pragma unroll
        for (int off = 16; off > 0; off >>= 1) {
            pp.x += __shfl_xor(pp.x, off);
            pp.y += __shfl_xor(pp.y, off);
            pp.z += __shfl_xor(pp.z, off);
            pp.w += __shfl_xor(pp.w, off);
        }
        if ((tid & 31) == 0) {
            float* ra = rowacc + (b * Wn + w0 + wloc) * 4;
            atomicAdd(ra + 0, pp.x);
            atomicAdd(ra + 1, pp.y);
            atomicAdd(ra + 2, pp.z);
            atomicAdd(ra + 3, pp.w);
        }
    }
    __syncthreads();

    // ---- ticket: last block computes the 4 scalars ----
    if (tid == 0) {
        __threadfence();
        const int old = atomicAdd(ticket, 1);
        lastFlag = (old == FG - 1) ? 1 : 0;
    }
    __syncthreads();
    if (lastFlag) {
        __threadfence();
        float se = 0.f, sn = 0.f, sc = 0.f;
        for (int r = tid; r < NROW; r += 256) {
            const float4 v = f4l(rowacc + r * 4);
            se += v.x;
            sn += sqrtf(v.x);
            sc += v.z / (fmaxf(sqrtf(v.y), EPSf) * fmaxf(sqrtf(v.w), EPSf));
        }
        #pragma unroll
        for (int off = 32; off > 0; off >>= 1) {
            se += __shfl_down(se, off);
            sn += __shfl_down(sn, off);
            sc += __shfl_down(sc, off);
        }
        float* rs = (float*)red;
        const int wv = tid >> 6, lane = tid & 63;
        if (lane == 0) { rs[wv * 3 + 0] = se; rs[wv * 3 + 1] = sn; rs[wv * 3 + 2] = sc; }
        __syncthreads();
        if (tid == 0) {
            float te = 0.f, tn = 0.f, tc = 0.f;
            #pragma unroll
            for (int i = 0; i < 4; ++i) {
                te += rs[i * 3 + 0]; tn += rs[i * 3 + 1]; tc += rs[i * 3 + 2];
            }
            const float inv = 1.0f / (float)NROW;
            const float pre = te * inv;
            const float om = 1.0f - alpha;
            const int base = Bn * Ln * Dn;
            out[base + 0] = pre;               // first_pre_energy
            out[base + 1] = om * om * pre;     // final_post_energy
            out[base + 2] = alpha * tn * inv;  // mean update norm
            out[base + 3] = tc * inv;          // mean cos sim
        }
    }
}

extern "C" void kernel_launch(void* const* d_in, const int* in_sizes, int n_in,
                              void* d_out, int out_size, void* d_ws, size_t ws_size,
                              hipStream_t stream)
{
    const float* x       = (const float*)d_in[0];
    const float* alpha_p = (const float*)d_in[1];
    const float* pos_emb = (const float*)d_in[2];
    const float* w1      = (const float*)d_in[3];
    const float* b1      = (const float*)d_in[4];
    const float* w2      = (const float*)d_in[5];
    const float* b2      = (const float*)d_in[6];
    float* out = (float*)d_out;

    // ws (floats): xw1 [2048*128] | pew1 [64*128] | rowacc [1922*4] | ticket [1]
    float* xw1    = (float*)d_ws;
    float* pew1   = xw1 + Bn * Ln * Hn;
    float* rowacc = pew1 + 64 * Hn;

    k_gemm1<<<G1, 512, 0, stream>>>(x, pos_emb, w1, b1, xw1, pew1, out, rowacc);
    k_fused<<<FG, 256, 0, stream>>>(x, alpha_p, w2, b2, xw1, pew1, out, rowacc);
}